// Round 3
// baseline (263.015 us; speedup 1.0000x reference)
//
#include <hip/hip_runtime.h>

// incidence_matrix_learn on MI355X — round 11.
// Round-10 post-mortem: halving MFMA work left duration UNCHANGED (88.7us).
// Invariant across r9/r10: total VMEM bytes (~622MB both). VGPR_Count
// 104-128 << declared live state (~200) => compiler re-SINKS the A-frag
// loads into the tile loop (legal: all-restrict), so r9's real traffic was
// ~1.1GB at ~20.4 B/cyc/CU — the m97-class VMEM delivery ceiling. Theory:
// VMEM-delivery-bound; fix = cut real bytes. This round: triangular tu-band
// blocks WITH A amortized across the tv sweep, A-frags PINNED in registers
// via empty asm uses (stops the re-sink; ~216 VGPR < 256 cap at 2 w/SIMD).
// Bytes: A 65MB + B 311MB = 376MB (0.34x of r9 real traffic).
// Also: prep split into prep_adj/prep_norm for per-dispatch visibility of
// the ~155us non-lse time.
// Validated algebra (rounds 1-10, absmax 0.0): top-k no-op; P via labels;
// fixed-shift-10 LSE; bf16 nhat; cnt = label-histogram - 1; counted-vmcnt
// ring staging; symmetric row+col harvest into disjoint sp slots.

#define DDIM 512
#define BATCH 64
#define NGID 65536   // 64*640 + 64*384 node-row slots across both scales

typedef __attribute__((ext_vector_type(8))) short short8;
typedef __attribute__((ext_vector_type(4))) float f32x4;

__device__ __forceinline__ unsigned short f2bf(float f) {
  unsigned int u = __float_as_uint(f);
  u += 0x7fffu + ((u >> 16) & 1u);   // RNE
  return (unsigned short)(u >> 16);
}

__device__ __forceinline__ void async16(const void* g, void* l) {
  __builtin_amdgcn_global_load_lds(
      (const __attribute__((address_space(1))) unsigned int*)g,
      (__attribute__((address_space(3))) unsigned int*)l, 16, 0, 0);
}

__device__ __forceinline__ int m3(int x) {  // x in [0, 12): x mod 3
  x -= (x >= 6) ? 6 : 0;
  x -= (x >= 3) ? 3 : 0;
  return x;
}

// adj path: 1024 blocks, 256 threads (one block per node row, both scales).
__global__ __launch_bounds__(256) void prep_adj(
    const float* __restrict__ enod0, const float* __restrict__ ehy0,
    const float* __restrict__ enod1, const float* __restrict__ ehy1,
    float* __restrict__ adj0, float* __restrict__ adj1,
    int* __restrict__ labels0, int* __restrict__ labels1,
    float* __restrict__ acc) {
  const int t = threadIdx.x;
  if (blockIdx.x == 0 && t == 0) { acc[0] = 0.f; acc[1] = 0.f; }
  const bool s0 = blockIdx.x < 640;
  const int n = s0 ? blockIdx.x : blockIdx.x - 640;
  const int H = s0 ? 128 : 64;
  const float* enod = s0 ? enod0 : enod1;
  const float* ehy = s0 ? ehy0 : ehy1;
  float* out_adj = s0 ? adj0 : adj1;
  int* labels = s0 ? labels0 : labels1;
  __shared__ float erow[DDIM];
  __shared__ float red[128];
  __shared__ int lab;
  if (t < 128) ((float4*)erow)[t] = ((const float4*)(enod + (size_t)n * DDIM))[t];
  if (t == 0) lab = -1;
  __syncthreads();
  float v = 0.f;
  if (t < H) {
    const float4* hr = (const float4*)(ehy + (size_t)t * DDIM);
    float a = 0.f;
    #pragma unroll 8
    for (int d = 0; d < DDIM / 4; ++d) {
      float4 h = hr[d];
      float4 e = ((const float4*)erow)[d];
      a = fmaf(h.x, e.x, a); a = fmaf(h.y, e.y, a);
      a = fmaf(h.z, e.z, a); a = fmaf(h.w, e.w, a);
    }
    v = fmaxf(0.f, 3.0f * a);
  }
  if (t < 128) red[t] = v;
  __syncthreads();
  for (int s = 64; s > 0; s >>= 1) {
    if (t < s) red[t] = fmaxf(red[t], red[t + s]);
    __syncthreads();
  }
  const float mx = red[0];
  __syncthreads();
  const float e = (t < H) ? __expf(v - mx) : 0.f;
  if (t < 128) red[t] = e;
  __syncthreads();
  for (int s = 64; s > 0; s >>= 1) {
    if (t < s) red[t] += red[t + s];
    __syncthreads();
  }
  const float sum = red[0];
  if (t < H) {
    const float adj = e / sum;
    const float bin = (adj > 0.5f) ? 1.0f : 0.0f;
    out_adj[(size_t)n * H + t] = bin;
    if (bin > 0.f) lab = t;
  }
  __syncthreads();
  if (t == 0) labels[n] = lab;
}

// normalize path: 16384 blocks, one WAVE per node row.
__global__ __launch_bounds__(256) void prep_norm(
    const float* __restrict__ x0, const float* __restrict__ w0,
    const float* __restrict__ x1, const float* __restrict__ w1,
    unsigned short* __restrict__ nhat0, unsigned short* __restrict__ nhat1) {
  const int t = threadIdx.x;
  const int wave = t >> 6;
  const int lane = t & 63;
  const int g = blockIdx.x * 4 + wave;   // global row id, < 65536
  const bool s0 = g < BATCH * 640;
  const int gg = s0 ? g : g - BATCH * 640;
  const int N = s0 ? 640 : 384;
  const int L = s0 ? 512 : 256;
  const float* x = s0 ? x0 : x1;
  const float* w = s0 ? w0 : w1;
  unsigned short* nhat = s0 ? nhat0 : nhat1;
  const int b = gg / N;
  const int n = gg - b * N;
  const float* src = (n < L) ? (x + ((size_t)b * L + n) * DDIM)
                             : (w + (size_t)(n - L) * DDIM);
  const float4* rowp = (const float4*)src;
  const float4 v0 = rowp[lane];
  const float4 v1 = rowp[lane + 64];
  float ss = v0.x * v0.x + v0.y * v0.y + v0.z * v0.z + v0.w * v0.w +
             v1.x * v1.x + v1.y * v1.y + v1.z * v1.z + v1.w * v1.w;
  #pragma unroll
  for (int off = 32; off > 0; off >>= 1) ss += __shfl_xor(ss, off);
  const float rinv = 1.0f / fmaxf(sqrtf(ss), 1e-12f);
  ushort4 o0, o1;
  o0.x = f2bf(v0.x * rinv); o0.y = f2bf(v0.y * rinv);
  o0.z = f2bf(v0.z * rinv); o0.w = f2bf(v0.w * rinv);
  o1.x = f2bf(v1.x * rinv); o1.y = f2bf(v1.y * rinv);
  o1.z = f2bf(v1.z * rinv); o1.w = f2bf(v1.w * rinv);
  ushort4* op = (ushort4*)(nhat + ((size_t)b * N + n) * DDIM);
  op[lane] = o0;
  op[lane + 64] = o1;
}

// 2 blocks. cnt[i] = hist[lab[i]] - 1 via 128-bin LDS label histogram.
__global__ __launch_bounds__(256) void cnt_kernel(
    const int* __restrict__ labels0, int* __restrict__ cnt0,
    const int* __restrict__ labels1, int* __restrict__ cnt1,
    int* __restrict__ valid) {
  const bool s0 = blockIdx.x == 0;
  const int* labels = s0 ? labels0 : labels1;
  int* cnt = s0 ? cnt0 : cnt1;
  int* validcnt = s0 ? valid : valid + 1;
  const int N = s0 ? 640 : 384;
  __shared__ int lab[640];
  __shared__ int hist[128];
  __shared__ int vc;
  const int t = threadIdx.x;
  if (t == 0) vc = 0;
  if (t < 128) hist[t] = 0;
  for (int i = t; i < N; i += 256) lab[i] = labels[i];
  __syncthreads();
  for (int i = t; i < N; i += 256)
    if (lab[i] >= 0) atomicAdd(&hist[lab[i]], 1);
  __syncthreads();
  int lv = 0;
  for (int i = t; i < N; i += 256) {
    const int c = (lab[i] >= 0) ? hist[lab[i]] - 1 : 0;
    cnt[i] = c;
    if (c > 0) ++lv;
  }
  if (lv > 0) atomicAdd(&vc, lv);
  __syncthreads();
  if (t == 0) *validcnt = vc;
}

// Triangular MFMA lse kernel, 128 threads (2 waves) per (scale, tu, b).
// Block owns a 64-row u-band, holds its A-frags (full K) PINNED in regs,
// and sweeps tv = tu..nt-1 as one continuous chunk stream (8 chunks of 64k
// per tile) through a ring-3 LDS with counted vmcnt (never 0 mid-stream).
// Row-sums accumulate in registers across the sweep -> one store (slot 0).
// Col-sums per off-diag tile -> cross-wave LDS combine (raw s_barrier +
// lgkmcnt only; in-flight prefetches preserved) -> store slot 1+tu.
// Every (slot,gid) in {0..band(gid)} is written exactly once, non-atomic.
__global__ __launch_bounds__(128, 2) void lse_kernel(
    const unsigned short* __restrict__ nhat0, const int* __restrict__ labels0,
    const unsigned short* __restrict__ nhat1, const int* __restrict__ labels1,
    float2* __restrict__ sp) {
  __shared__ short8 Bbuf[3][512];   // ring-3 x 8 KB, frag-order
  __shared__ float2 redC[2][64];    // cross-wave col-sum combine
  __shared__ int labS[640];
  const int tid = threadIdx.x;
  const bool s0 = blockIdx.x < 640;
  const int i = s0 ? blockIdx.x : blockIdx.x - 640;
  const int tu = i >> 6;           // heavy (small tu) blocks first
  const int b = i & 63;
  const int nt = s0 ? 10 : 6;
  const int N = s0 ? 640 : 384;
  const unsigned short* nhat = s0 ? nhat0 : nhat1;
  const int* labels = s0 ? labels0 : labels1;
  const int gbase = s0 ? b * 640 : 40960 + b * 384;

  const int wave = tid >> 6;   // 0..1
  const int lane = tid & 63;
  const int lrow = lane & 15;   // A-row within 16 / B-col / C-col
  const int lq = lane >> 4;     // k-chunk selector / C row group

  for (int t = tid; t < N; t += 128) labS[t] = labels[t];

  const size_t base = (size_t)b * N * DDIM;
  const int rw0 = tu * 64 + wave * 32;   // wave owns u-rows rw0 .. rw0+31
  const unsigned short* Ap0 = nhat + base + (size_t)(rw0 + lrow) * DDIM + lq * 8;
  const unsigned short* Ap1 = Ap0 + (size_t)16 * DDIM;
  short8 a0[16], a1[16];
  #pragma unroll
  for (int ks = 0; ks < 16; ++ks) {
    a0[ks] = *(const short8*)(Ap0 + ks * 32);
    a1[ks] = *(const short8*)(Ap1 + ks * 32);
  }
  // Pin A-frags in VGPRs: empty asm uses stop the compiler from re-sinking
  // these loads into the tv loop (the r9/r10 hidden-traffic bug).
  #pragma unroll
  for (int ks = 0; ks < 16; ++ks)
    asm volatile("" :: "v"(a0[ks]), "v"(a1[ks]));

  __syncthreads();   // labS visible; full vmcnt drain: ring counting clean

  int labn[2][4];
  #pragma unroll
  for (int s = 0; s < 2; ++s)
    #pragma unroll
    for (int r = 0; r < 4; ++r) labn[s][r] = labS[rw0 + s * 16 + lq * 4 + r];

  // prologue: chunks 0,1 of tile tu -> slots 0,1 (4 frags per wave per chunk)
  const unsigned short* Bp0 = nhat + base + (size_t)tu * 64 * DDIM;
  const int f0 = wave * 4;
  #pragma unroll
  for (int pc = 0; pc < 2; ++pc) {
    #pragma unroll
    for (int fi = 0; fi < 4; ++fi) {
      const int f = f0 + fi, j = f >> 1, ks = f & 1;
      async16(Bp0 + (size_t)(j * 16 + lrow) * DDIM + pc * 64 + ks * 32 + lq * 8,
              &Bbuf[pc][f * 64]);
    }
  }

  float rSE[2][4] = {{0.f, 0.f, 0.f, 0.f}, {0.f, 0.f, 0.f, 0.f}};
  float rPOS[2][4] = {{0.f, 0.f, 0.f, 0.f}, {0.f, 0.f, 0.f, 0.f}};
  int slotb = 0;   // ring slot of kc=0 for the current tile

  for (int tv = tu; tv < nt; ++tv) {
    const bool diag = (tv == tu);
    const bool last = (tv == nt - 1);
    const unsigned short* Bcur = nhat + base + (size_t)tv * 64 * DDIM;
    const unsigned short* Bnxt = Bcur + (size_t)64 * DDIM;
    const int sl[3] = {slotb, m3(slotb + 1), m3(slotb + 2)};

    f32x4 acc[4][2];
    #pragma unroll
    for (int j = 0; j < 4; ++j) {
      acc[j][0] = (f32x4){0.f, 0.f, 0.f, 0.f};
      acc[j][1] = (f32x4){0.f, 0.f, 0.f, 0.f};
    }
    #pragma unroll
    for (int kc = 0; kc < 8; ++kc) {
      // own 4 loads of this chunk done; next chunk's (and possibly an
      // epilogue store) stay in flight. Over-waits are harmless.
      if (last && kc == 7) asm volatile("s_waitcnt vmcnt(0)" ::: "memory");
      else                 asm volatile("s_waitcnt vmcnt(4)" ::: "memory");
      __builtin_amdgcn_s_barrier();   // both waves' chunk loads landed;
                                      // readers of slot being refilled done
      if (!(last && kc >= 6)) {
        const unsigned short* Bsrc = (kc < 6) ? Bcur : Bnxt;
        const int kcol = (kc < 6) ? kc + 2 : kc - 6;
        short8* dst = &Bbuf[sl[(kc + 2) % 3]][0];
        #pragma unroll
        for (int fi = 0; fi < 4; ++fi) {
          const int f = f0 + fi, j = f >> 1, ks = f & 1;
          async16(Bsrc + (size_t)(j * 16 + lrow) * DDIM + kcol * 64 + ks * 32 + lq * 8,
                  dst + f * 64);
        }
      }
      const short8* bb = &Bbuf[sl[kc % 3]][0];
      #pragma unroll
      for (int ks = 0; ks < 2; ++ks) {
        const short8 b0 = bb[(0 + ks) * 64 + lane];
        const short8 b1 = bb[(2 + ks) * 64 + lane];
        const short8 b2 = bb[(4 + ks) * 64 + lane];
        const short8 b3 = bb[(6 + ks) * 64 + lane];
        const short8 av0 = a0[kc * 2 + ks];
        const short8 av1 = a1[kc * 2 + ks];
        acc[0][0] = __builtin_amdgcn_mfma_f32_16x16x32_bf16(av0, b0, acc[0][0], 0, 0, 0);
        acc[0][1] = __builtin_amdgcn_mfma_f32_16x16x32_bf16(av1, b0, acc[0][1], 0, 0, 0);
        acc[1][0] = __builtin_amdgcn_mfma_f32_16x16x32_bf16(av0, b1, acc[1][0], 0, 0, 0);
        acc[1][1] = __builtin_amdgcn_mfma_f32_16x16x32_bf16(av1, b1, acc[1][1], 0, 0, 0);
        acc[2][0] = __builtin_amdgcn_mfma_f32_16x16x32_bf16(av0, b2, acc[2][0], 0, 0, 0);
        acc[2][1] = __builtin_amdgcn_mfma_f32_16x16x32_bf16(av1, b2, acc[2][1], 0, 0, 0);
        acc[3][0] = __builtin_amdgcn_mfma_f32_16x16x32_bf16(av0, b3, acc[3][0], 0, 0, 0);
        acc[3][1] = __builtin_amdgcn_mfma_f32_16x16x32_bf16(av1, b3, acc[3][1], 0, 0, 0);
      }
    }

    // per-tile harvest: row-side accumulates in regs; col-side per tile
    float cSE[4] = {0.f, 0.f, 0.f, 0.f};
    float cPOS[4] = {0.f, 0.f, 0.f, 0.f};
    #pragma unroll
    for (int j = 0; j < 4; ++j) {
      const int v = tv * 64 + j * 16 + lrow;
      const int labm = labS[v];
      #pragma unroll
      for (int s = 0; s < 2; ++s) {
        const int u0 = rw0 + s * 16 + lq * 4;
        #pragma unroll
        for (int r = 0; r < 4; ++r) {
          const float sim = acc[j][s][r] * 10.0f;    // 1/TAU
          const float e = __expf(sim - 10.0f);       // fixed shift (diag max)
          rSE[s][r] += e;
          const bool match = (labn[s][r] >= 0) && (labm == labn[s][r]);
          if (match && v != u0 + r) rPOS[s][r] += sim;
          if (!diag) {
            cSE[j] += e;
            if (match) cPOS[j] += sim;   // u != v automatic off-diag
          }
        }
      }
    }
    if (!diag) {
      // col reduce across lq groups (lanes ^16, ^32)
      #pragma unroll
      for (int off = 16; off <= 32; off <<= 1) {
        #pragma unroll
        for (int j = 0; j < 4; ++j) {
          cSE[j] += __shfl_xor(cSE[j], off);
          cPOS[j] += __shfl_xor(cPOS[j], off);
        }
      }
      if (lane < 16) {
        #pragma unroll
        for (int j = 0; j < 4; ++j) {
          float2 st; st.x = cSE[j]; st.y = cPOS[j];
          redC[wave][j * 16 + lane] = st;
        }
      }
      // cross-wave combine WITHOUT draining vmcnt (prefetches in flight):
      asm volatile("s_waitcnt lgkmcnt(0)" ::: "memory");
      __builtin_amdgcn_s_barrier();
      if (lane < 32) {
        const int v = wave * 32 + lane;      // both waves store half: vmcnt
        const float2 c0 = redC[0][v];        // stays symmetric across waves
        const float2 c1 = redC[1][v];
        float2 st; st.x = c0.x + c1.x; st.y = c0.y + c1.y;
        sp[(size_t)(1 + tu) * NGID + gbase + tv * 64 + v] = st;
      }
      // redC reuse next tile is separated by >=1 chunk-top barrier
    }
    slotb = m3(slotb + 2);   // 8 chunks advance ring by 8 mod 3 = 2
  }

  // row reduce across the 16 col-lanes, store slot 0
  #pragma unroll
  for (int off = 1; off <= 8; off <<= 1) {
    #pragma unroll
    for (int s = 0; s < 2; ++s)
      #pragma unroll
      for (int r = 0; r < 4; ++r) {
        rSE[s][r] += __shfl_xor(rSE[s][r], off);
        rPOS[s][r] += __shfl_xor(rPOS[s][r], off);
      }
  }
  if (lrow == 0) {
    #pragma unroll
    for (int s = 0; s < 2; ++s)
      #pragma unroll
      for (int r = 0; r < 4; ++r) {
        const int u = rw0 + s * 16 + lq * 4 + r;
        float2 st; st.x = rSE[s][r]; st.y = rPOS[s][r];
        sp[gbase + u] = st;   // slot 0
      }
  }
}

// Sum per-gid partials over slots 0..band(gid), apply LSE + pos/cnt, reduce.
__global__ __launch_bounds__(256) void loss_reduce(
    const float2* __restrict__ sp, const int* __restrict__ cnt0,
    const int* __restrict__ cnt1, float* __restrict__ acc) {
  __shared__ float r0[4], r1[4];
  const int t = threadIdx.x;
  float l0 = 0.f, l1 = 0.f;
  for (int g = blockIdx.x * 256 + t; g < NGID; g += 64 * 256) {
    const bool is0 = g < 40960;
    const int n = is0 ? (g % 640) : ((g - 40960) % 384);
    const int tb = n >> 6;   // band index: slots 0..tb are populated
    float se = 0.f, pos = 0.f;
    for (int s = 0; s <= tb; ++s) {
      const float2 v = sp[(size_t)s * NGID + g];
      se += v.x; pos += v.y;
    }
    const int c = is0 ? cnt0[n] : cnt1[n];
    if (c > 0) {
      const float v = (10.0f + logf(se)) - pos / (float)c;
      if (is0) l0 += v; else l1 += v;
    }
  }
  #pragma unroll
  for (int off = 32; off > 0; off >>= 1) {
    l0 += __shfl_xor(l0, off);
    l1 += __shfl_xor(l1, off);
  }
  if ((t & 63) == 0) { r0[t >> 6] = l0; r1[t >> 6] = l1; }
  __syncthreads();
  if (t == 0) {
    atomicAdd(&acc[0], r0[0] + r0[1] + r0[2] + r0[3]);
    atomicAdd(&acc[1], r1[0] + r1[1] + r1[2] + r1[3]);
  }
}

__global__ void final_kernel(const float* __restrict__ acc,
                             const int* __restrict__ valid,
                             float* __restrict__ out) {
  float l = 0.f;
  if (valid[0] > 0) l += acc[0] / (float)(BATCH * valid[0]);
  if (valid[1] > 0) l += acc[1] / (float)(BATCH * valid[1]);
  out[0] = l;
}

extern "C" void kernel_launch(void* const* d_in, const int* in_sizes, int n_in,
                              void* d_out, int out_size, void* d_ws,
                              size_t ws_size, hipStream_t stream) {
  const float* x0 = (const float*)d_in[0];
  const float* x1 = (const float*)d_in[1];
  const float* w0 = (const float*)d_in[2];
  const float* w1 = (const float*)d_in[3];
  const float* ehy0 = (const float*)d_in[4];
  const float* ehy1 = (const float*)d_in[5];
  const float* enod0 = (const float*)d_in[6];
  const float* enod1 = (const float*)d_in[7];

  float* out = (float*)d_out;
  float* adj0 = out;                       // 640*128
  float* adj1 = out + 640 * 128;           // 384*64
  float* lossp = out + 640 * 128 + 384 * 64;

  unsigned short* nhat0 = (unsigned short*)d_ws;
  unsigned short* nhat1 = nhat0 + (size_t)BATCH * 640 * DDIM;
  int* ip = (int*)(nhat1 + (size_t)BATCH * 384 * DDIM);
  int* labels0 = ip;
  int* labels1 = labels0 + 640;
  int* cnt0 = labels1 + 384;
  int* cnt1 = cnt0 + 640;
  int* valid = cnt1 + 384;
  float* acc = (float*)(valid + 2);
  float2* sp = (float2*)((((size_t)(acc + 2)) + 255) & ~(size_t)255);
  // sp: 10 slots x 65536 gids x 8 B = 5.24 MB (ws total ~72.4 MB)

  prep_adj<<<1024, 256, 0, stream>>>(enod0, ehy0, enod1, ehy1, adj0, adj1,
                                     labels0, labels1, acc);
  prep_norm<<<16384, 256, 0, stream>>>(x0, w0, x1, w1, nhat0, nhat1);
  cnt_kernel<<<2, 256, 0, stream>>>(labels0, cnt0, labels1, cnt1, valid);
  lse_kernel<<<1024, 128, 0, stream>>>(nhat0, labels0, nhat1, labels1, sp);
  loss_reduce<<<64, 256, 0, stream>>>(sp, cnt0, cnt1, acc);
  final_kernel<<<1, 1, 0, stream>>>(acc, valid, lossp);
}

// Round 4
// 252.248 us; speedup vs baseline: 1.0427x; 1.0427x over previous
//
#include <hip/hip_runtime.h>

// incidence_matrix_learn on MI355X — round 12.
// Round-11 post-mortem: input-only asm pin FAILED (VGPR_Count still 128;
// FETCH tripled to 147MB = A re-fetched per tile). Compiler rematerializes
// past "v"-input pins. The re-sunk A-loads also increment vmcnt INSIDE the
// counted-wait stream -> pipeline discipline scrambled (explains r9 null).
// Invariant across r9/r10/r11: ~600+MB real VMEM <-> ~86-92us.
// Fix: READ-WRITE pins ("+v") at each tv-iteration top — asm may modify the
// value, so reload-from-memory is illegal -> A (128 VGPRs) stays live.
// Peak pressure ~240 <= 256 cap of __launch_bounds__(128,2).
// Also: 16-entry band permutation so each CU class (4 co-resident blocks)
// sums to exactly 19 tile-units (was 22/18/14/10 -> 16% tail waste);
// re-fused prep; final folded into loss_reduce via device ticket.
// Validated algebra (rounds 1-11, absmax 0.0): top-k no-op; P via labels;
// fixed-shift-10 LSE; bf16 nhat; cnt = label-histogram - 1; counted-vmcnt
// ring staging; triangular row+col harvest into disjoint sp slots.

#define DDIM 512
#define BATCH 64
#define NGID 65536   // 64*640 + 64*384 node-row slots across both scales

typedef __attribute__((ext_vector_type(8))) short short8;
typedef __attribute__((ext_vector_type(4))) float f32x4;

// Band schedule: pos = blockIdx>>6 indexes 16 bands (10 of scale0, 6 of
// scale1). Under round-robin CU assignment, CU class t gets positions
// {t, t+4, t+8, t+12}; this permutation makes each class sum to 19 units:
// {10,1,6,2} {9,1,5,4} {8,3,5,3} {7,6,4,2}.
__constant__ int POS_SCALE[16] = {0,0,0,0, 0,1,0,0, 1,1,0,0, 0,1,1,1};
__constant__ int POS_TU[16]    = {0,1,2,3, 9,5,7,4, 0,1,5,6, 8,2,3,4};

__device__ __forceinline__ unsigned short f2bf(float f) {
  unsigned int u = __float_as_uint(f);
  u += 0x7fffu + ((u >> 16) & 1u);   // RNE
  return (unsigned short)(u >> 16);
}

__device__ __forceinline__ void async16(const void* g, void* l) {
  __builtin_amdgcn_global_load_lds(
      (const __attribute__((address_space(1))) unsigned int*)g,
      (__attribute__((address_space(3))) unsigned int*)l, 16, 0, 0);
}

__device__ __forceinline__ int m3(int x) {  // x in [0, 12): x mod 3
  x -= (x >= 6) ? 6 : 0;
  x -= (x >= 3) ? 3 : 0;
  return x;
}

// Fused prep kernel, 256 threads. Blocks [0,1024): adj (both scales) + acc/
// ticket init. Blocks [1024, 1024+16384): normalize, one WAVE per node row.
__global__ __launch_bounds__(256) void prep_kernel(
    const float* __restrict__ enod0, const float* __restrict__ ehy0,
    const float* __restrict__ enod1, const float* __restrict__ ehy1,
    float* __restrict__ adj0, float* __restrict__ adj1,
    int* __restrict__ labels0, int* __restrict__ labels1,
    const float* __restrict__ x0, const float* __restrict__ w0,
    const float* __restrict__ x1, const float* __restrict__ w1,
    unsigned short* __restrict__ nhat0, unsigned short* __restrict__ nhat1,
    float* __restrict__ acc, int* __restrict__ ticket) {
  const int t = threadIdx.x;
  if (blockIdx.x < 1024) {
    // ---- adj path ----
    if (blockIdx.x == 0 && t == 0) { acc[0] = 0.f; acc[1] = 0.f; ticket[0] = 0; }
    const bool s0 = blockIdx.x < 640;
    const int n = s0 ? blockIdx.x : blockIdx.x - 640;
    const int H = s0 ? 128 : 64;
    const float* enod = s0 ? enod0 : enod1;
    const float* ehy = s0 ? ehy0 : ehy1;
    float* out_adj = s0 ? adj0 : adj1;
    int* labels = s0 ? labels0 : labels1;
    __shared__ float erow[DDIM];
    __shared__ float red[128];
    __shared__ int lab;
    if (t < 128) ((float4*)erow)[t] = ((const float4*)(enod + (size_t)n * DDIM))[t];
    if (t == 0) lab = -1;
    __syncthreads();
    float v = 0.f;
    if (t < H) {
      const float4* hr = (const float4*)(ehy + (size_t)t * DDIM);
      float a = 0.f;
      #pragma unroll 8
      for (int d = 0; d < DDIM / 4; ++d) {
        float4 h = hr[d];
        float4 e = ((const float4*)erow)[d];
        a = fmaf(h.x, e.x, a); a = fmaf(h.y, e.y, a);
        a = fmaf(h.z, e.z, a); a = fmaf(h.w, e.w, a);
      }
      v = fmaxf(0.f, 3.0f * a);
    }
    if (t < 128) red[t] = v;
    __syncthreads();
    for (int s = 64; s > 0; s >>= 1) {
      if (t < s) red[t] = fmaxf(red[t], red[t + s]);
      __syncthreads();
    }
    const float mx = red[0];
    __syncthreads();
    const float e = (t < H) ? __expf(v - mx) : 0.f;
    if (t < 128) red[t] = e;
    __syncthreads();
    for (int s = 64; s > 0; s >>= 1) {
      if (t < s) red[t] += red[t + s];
      __syncthreads();
    }
    const float sum = red[0];
    if (t < H) {
      const float adj = e / sum;
      const float bin = (adj > 0.5f) ? 1.0f : 0.0f;
      out_adj[(size_t)n * H + t] = bin;
      if (bin > 0.f) lab = t;
    }
    __syncthreads();
    if (t == 0) labels[n] = lab;
  } else {
    // ---- normalize path: wave per row ----
    const int wave = t >> 6;
    const int lane = t & 63;
    const int g = (blockIdx.x - 1024) * 4 + wave;   // global row id, < 65536
    const bool s0 = g < BATCH * 640;
    const int gg = s0 ? g : g - BATCH * 640;
    const int N = s0 ? 640 : 384;
    const int L = s0 ? 512 : 256;
    const float* x = s0 ? x0 : x1;
    const float* w = s0 ? w0 : w1;
    unsigned short* nhat = s0 ? nhat0 : nhat1;
    const int b = gg / N;
    const int n = gg - b * N;
    const float* src = (n < L) ? (x + ((size_t)b * L + n) * DDIM)
                               : (w + (size_t)(n - L) * DDIM);
    const float4* rowp = (const float4*)src;
    const float4 v0 = rowp[lane];
    const float4 v1 = rowp[lane + 64];
    float ss = v0.x * v0.x + v0.y * v0.y + v0.z * v0.z + v0.w * v0.w +
               v1.x * v1.x + v1.y * v1.y + v1.z * v1.z + v1.w * v1.w;
    #pragma unroll
    for (int off = 32; off > 0; off >>= 1) ss += __shfl_xor(ss, off);
    const float rinv = 1.0f / fmaxf(sqrtf(ss), 1e-12f);
    ushort4 o0, o1;
    o0.x = f2bf(v0.x * rinv); o0.y = f2bf(v0.y * rinv);
    o0.z = f2bf(v0.z * rinv); o0.w = f2bf(v0.w * rinv);
    o1.x = f2bf(v1.x * rinv); o1.y = f2bf(v1.y * rinv);
    o1.z = f2bf(v1.z * rinv); o1.w = f2bf(v1.w * rinv);
    ushort4* op = (ushort4*)(nhat + ((size_t)b * N + n) * DDIM);
    op[lane] = o0;
    op[lane + 64] = o1;
  }
}

// 2 blocks. cnt[i] = hist[lab[i]] - 1 via 128-bin LDS label histogram.
__global__ __launch_bounds__(256) void cnt_kernel(
    const int* __restrict__ labels0, int* __restrict__ cnt0,
    const int* __restrict__ labels1, int* __restrict__ cnt1,
    int* __restrict__ valid) {
  const bool s0 = blockIdx.x == 0;
  const int* labels = s0 ? labels0 : labels1;
  int* cnt = s0 ? cnt0 : cnt1;
  int* validcnt = s0 ? valid : valid + 1;
  const int N = s0 ? 640 : 384;
  __shared__ int lab[640];
  __shared__ int hist[128];
  __shared__ int vc;
  const int t = threadIdx.x;
  if (t == 0) vc = 0;
  if (t < 128) hist[t] = 0;
  for (int i = t; i < N; i += 256) lab[i] = labels[i];
  __syncthreads();
  for (int i = t; i < N; i += 256)
    if (lab[i] >= 0) atomicAdd(&hist[lab[i]], 1);
  __syncthreads();
  int lv = 0;
  for (int i = t; i < N; i += 256) {
    const int c = (lab[i] >= 0) ? hist[lab[i]] - 1 : 0;
    cnt[i] = c;
    if (c > 0) ++lv;
  }
  if (lv > 0) atomicAdd(&vc, lv);
  __syncthreads();
  if (t == 0) *validcnt = vc;
}

// Triangular MFMA lse kernel, 128 threads (2 waves) per (band-pos, b).
// Block owns a 64-row u-band, holds its A-frags (full K) pinned live in
// registers ("+v" pins each tile), sweeps tv = tu..nt-1 as one continuous
// chunk stream (8 chunks of 64k per tile) through a ring-3 LDS with counted
// vmcnt (never 0 mid-stream). Row-sums accumulate in regs -> slot 0;
// col-sums per off-diag tile -> cross-wave LDS combine -> slot 1+tu.
__global__ __launch_bounds__(128, 2) void lse_kernel(
    const unsigned short* __restrict__ nhat0, const int* __restrict__ labels0,
    const unsigned short* __restrict__ nhat1, const int* __restrict__ labels1,
    float2* __restrict__ sp) {
  __shared__ short8 Bbuf[3][512];   // ring-3 x 8 KB, frag-order
  __shared__ float2 redC[2][64];    // cross-wave col-sum combine
  __shared__ int labS[640];
  const int tid = threadIdx.x;
  const int pos = blockIdx.x >> 6;
  const int b = blockIdx.x & 63;
  const bool s0 = POS_SCALE[pos] == 0;
  const int tu = POS_TU[pos];
  const int nt = s0 ? 10 : 6;
  const int N = s0 ? 640 : 384;
  const unsigned short* nhat = s0 ? nhat0 : nhat1;
  const int* labels = s0 ? labels0 : labels1;
  const int gbase = s0 ? b * 640 : 40960 + b * 384;

  const int wave = tid >> 6;   // 0..1
  const int lane = tid & 63;
  const int lrow = lane & 15;   // A-row within 16 / B-col / C-col
  const int lq = lane >> 4;     // k-chunk selector / C row group

  for (int t = tid; t < N; t += 128) labS[t] = labels[t];

  const size_t base = (size_t)b * N * DDIM;
  const int rw0 = tu * 64 + wave * 32;   // wave owns u-rows rw0 .. rw0+31
  const unsigned short* Ap0 = nhat + base + (size_t)(rw0 + lrow) * DDIM + lq * 8;
  const unsigned short* Ap1 = Ap0 + (size_t)16 * DDIM;
  short8 a0[16], a1[16];
  #pragma unroll
  for (int ks = 0; ks < 16; ++ks) {
    a0[ks] = *(const short8*)(Ap0 + ks * 32);
    a1[ks] = *(const short8*)(Ap1 + ks * 32);
  }

  __syncthreads();   // labS visible; full vmcnt drain: ring counting clean

  int labn[2][4];
  #pragma unroll
  for (int s = 0; s < 2; ++s)
    #pragma unroll
    for (int r = 0; r < 4; ++r) labn[s][r] = labS[rw0 + s * 16 + lq * 4 + r];

  // prologue: chunks 0,1 of tile tu -> slots 0,1 (4 frags per wave per chunk)
  const unsigned short* Bp0 = nhat + base + (size_t)tu * 64 * DDIM;
  const int f0 = wave * 4;
  #pragma unroll
  for (int pc = 0; pc < 2; ++pc) {
    #pragma unroll
    for (int fi = 0; fi < 4; ++fi) {
      const int f = f0 + fi, j = f >> 1, ks = f & 1;
      async16(Bp0 + (size_t)(j * 16 + lrow) * DDIM + pc * 64 + ks * 32 + lq * 8,
              &Bbuf[pc][f * 64]);
    }
  }

  float rSE[2][4] = {{0.f, 0.f, 0.f, 0.f}, {0.f, 0.f, 0.f, 0.f}};
  float rPOS[2][4] = {{0.f, 0.f, 0.f, 0.f}, {0.f, 0.f, 0.f, 0.f}};
  int slotb = 0;   // ring slot of kc=0 for the current tile

  for (int tv = tu; tv < nt; ++tv) {
    // READ-WRITE pins: the asm may modify a0/a1, so the compiler cannot
    // rematerialize them by re-loading from global — A stays in VGPRs for
    // the whole sweep (the r9/r11 hidden-traffic + vmcnt-scramble bug).
    asm volatile("" : "+v"(a0[0]), "+v"(a0[1]), "+v"(a0[2]), "+v"(a0[3]),
                      "+v"(a0[4]), "+v"(a0[5]), "+v"(a0[6]), "+v"(a0[7]));
    asm volatile("" : "+v"(a0[8]), "+v"(a0[9]), "+v"(a0[10]), "+v"(a0[11]),
                      "+v"(a0[12]), "+v"(a0[13]), "+v"(a0[14]), "+v"(a0[15]));
    asm volatile("" : "+v"(a1[0]), "+v"(a1[1]), "+v"(a1[2]), "+v"(a1[3]),
                      "+v"(a1[4]), "+v"(a1[5]), "+v"(a1[6]), "+v"(a1[7]));
    asm volatile("" : "+v"(a1[8]), "+v"(a1[9]), "+v"(a1[10]), "+v"(a1[11]),
                      "+v"(a1[12]), "+v"(a1[13]), "+v"(a1[14]), "+v"(a1[15]));
    const bool diag = (tv == tu);
    const bool last = (tv == nt - 1);
    const unsigned short* Bcur = nhat + base + (size_t)tv * 64 * DDIM;
    const unsigned short* Bnxt = Bcur + (size_t)64 * DDIM;
    const int sl[3] = {slotb, m3(slotb + 1), m3(slotb + 2)};

    f32x4 acc[4][2];
    #pragma unroll
    for (int j = 0; j < 4; ++j) {
      acc[j][0] = (f32x4){0.f, 0.f, 0.f, 0.f};
      acc[j][1] = (f32x4){0.f, 0.f, 0.f, 0.f};
    }
    #pragma unroll
    for (int kc = 0; kc < 8; ++kc) {
      // own 4 loads of this chunk done; next chunk's (and possibly the
      // tile-epilogue store) stay in flight. Over-waits are harmless.
      if (last && kc == 7) asm volatile("s_waitcnt vmcnt(0)" ::: "memory");
      else                 asm volatile("s_waitcnt vmcnt(4)" ::: "memory");
      __builtin_amdgcn_s_barrier();   // both waves' chunk loads landed;
                                      // readers of slot being refilled done
      if (!(last && kc >= 6)) {
        const unsigned short* Bsrc = (kc < 6) ? Bcur : Bnxt;
        const int kcol = (kc < 6) ? kc + 2 : kc - 6;
        short8* dst = &Bbuf[sl[(kc + 2) % 3]][0];
        #pragma unroll
        for (int fi = 0; fi < 4; ++fi) {
          const int f = f0 + fi, j = f >> 1, ks = f & 1;
          async16(Bsrc + (size_t)(j * 16 + lrow) * DDIM + kcol * 64 + ks * 32 + lq * 8,
                  dst + f * 64);
        }
      }
      const short8* bb = &Bbuf[sl[kc % 3]][0];
      #pragma unroll
      for (int ks = 0; ks < 2; ++ks) {
        const short8 b0 = bb[(0 + ks) * 64 + lane];
        const short8 b1 = bb[(2 + ks) * 64 + lane];
        const short8 b2 = bb[(4 + ks) * 64 + lane];
        const short8 b3 = bb[(6 + ks) * 64 + lane];
        const short8 av0 = a0[kc * 2 + ks];
        const short8 av1 = a1[kc * 2 + ks];
        acc[0][0] = __builtin_amdgcn_mfma_f32_16x16x32_bf16(av0, b0, acc[0][0], 0, 0, 0);
        acc[0][1] = __builtin_amdgcn_mfma_f32_16x16x32_bf16(av1, b0, acc[0][1], 0, 0, 0);
        acc[1][0] = __builtin_amdgcn_mfma_f32_16x16x32_bf16(av0, b1, acc[1][0], 0, 0, 0);
        acc[1][1] = __builtin_amdgcn_mfma_f32_16x16x32_bf16(av1, b1, acc[1][1], 0, 0, 0);
        acc[2][0] = __builtin_amdgcn_mfma_f32_16x16x32_bf16(av0, b2, acc[2][0], 0, 0, 0);
        acc[2][1] = __builtin_amdgcn_mfma_f32_16x16x32_bf16(av1, b2, acc[2][1], 0, 0, 0);
        acc[3][0] = __builtin_amdgcn_mfma_f32_16x16x32_bf16(av0, b3, acc[3][0], 0, 0, 0);
        acc[3][1] = __builtin_amdgcn_mfma_f32_16x16x32_bf16(av1, b3, acc[3][1], 0, 0, 0);
      }
    }

    // per-tile harvest: row-side accumulates in regs; col-side per tile
    float cSE[4] = {0.f, 0.f, 0.f, 0.f};
    float cPOS[4] = {0.f, 0.f, 0.f, 0.f};
    #pragma unroll
    for (int j = 0; j < 4; ++j) {
      const int v = tv * 64 + j * 16 + lrow;
      const int labm = labS[v];
      #pragma unroll
      for (int s = 0; s < 2; ++s) {
        const int u0 = rw0 + s * 16 + lq * 4;
        #pragma unroll
        for (int r = 0; r < 4; ++r) {
          const float sim = acc[j][s][r] * 10.0f;    // 1/TAU
          const float e = __expf(sim - 10.0f);       // fixed shift (diag max)
          rSE[s][r] += e;
          const bool match = (labn[s][r] >= 0) && (labm == labn[s][r]);
          if (match && v != u0 + r) rPOS[s][r] += sim;
          if (!diag) {
            cSE[j] += e;
            if (match) cPOS[j] += sim;   // u != v automatic off-diag
          }
        }
      }
    }
    if (!diag) {
      // col reduce across lq groups (lanes ^16, ^32)
      #pragma unroll
      for (int off = 16; off <= 32; off <<= 1) {
        #pragma unroll
        for (int j = 0; j < 4; ++j) {
          cSE[j] += __shfl_xor(cSE[j], off);
          cPOS[j] += __shfl_xor(cPOS[j], off);
        }
      }
      if (lane < 16) {
        #pragma unroll
        for (int j = 0; j < 4; ++j) {
          float2 st; st.x = cSE[j]; st.y = cPOS[j];
          redC[wave][j * 16 + lane] = st;
        }
      }
      // cross-wave combine WITHOUT draining vmcnt (prefetches in flight):
      asm volatile("s_waitcnt lgkmcnt(0)" ::: "memory");
      __builtin_amdgcn_s_barrier();
      if (lane < 32) {
        const int v = wave * 32 + lane;      // both waves store half: vmcnt
        const float2 c0 = redC[0][v];        // stays symmetric across waves
        const float2 c1 = redC[1][v];
        float2 st; st.x = c0.x + c1.x; st.y = c0.y + c1.y;
        sp[(size_t)(1 + tu) * NGID + gbase + tv * 64 + v] = st;
      }
      // redC reuse next tile is separated by >=1 chunk-top barrier
    }
    slotb = m3(slotb + 2);   // 8 chunks advance ring by 8 mod 3 = 2
  }

  // row reduce across the 16 col-lanes, store slot 0
  #pragma unroll
  for (int off = 1; off <= 8; off <<= 1) {
    #pragma unroll
    for (int s = 0; s < 2; ++s)
      #pragma unroll
      for (int r = 0; r < 4; ++r) {
        rSE[s][r] += __shfl_xor(rSE[s][r], off);
        rPOS[s][r] += __shfl_xor(rPOS[s][r], off);
      }
  }
  if (lrow == 0) {
    #pragma unroll
    for (int s = 0; s < 2; ++s)
      #pragma unroll
      for (int r = 0; r < 4; ++r) {
        const int u = rw0 + s * 16 + lq * 4 + r;
        float2 st; st.x = rSE[s][r]; st.y = rPOS[s][r];
        sp[gbase + u] = st;   // slot 0
      }
  }
}

// Sum per-gid partials over slots 0..band(gid), apply LSE + pos/cnt, reduce.
// Last block (device ticket) folds acc/valid into the final loss scalar.
__global__ __launch_bounds__(256) void loss_reduce(
    const float2* __restrict__ sp, const int* __restrict__ cnt0,
    const int* __restrict__ cnt1, float* __restrict__ acc,
    const int* __restrict__ valid, int* __restrict__ ticket,
    float* __restrict__ lossp) {
  __shared__ float r0[4], r1[4];
  const int t = threadIdx.x;
  float l0 = 0.f, l1 = 0.f;
  for (int g = blockIdx.x * 256 + t; g < NGID; g += 64 * 256) {
    const bool is0 = g < 40960;
    const int n = is0 ? (g % 640) : ((g - 40960) % 384);
    const int tb = n >> 6;   // band index: slots 0..tb are populated
    float se = 0.f, pos = 0.f;
    for (int s = 0; s <= tb; ++s) {
      const float2 v = sp[(size_t)s * NGID + g];
      se += v.x; pos += v.y;
    }
    const int c = is0 ? cnt0[n] : cnt1[n];
    if (c > 0) {
      const float v = (10.0f + logf(se)) - pos / (float)c;
      if (is0) l0 += v; else l1 += v;
    }
  }
  #pragma unroll
  for (int off = 32; off > 0; off >>= 1) {
    l0 += __shfl_xor(l0, off);
    l1 += __shfl_xor(l1, off);
  }
  if ((t & 63) == 0) { r0[t >> 6] = l0; r1[t >> 6] = l1; }
  __syncthreads();
  if (t == 0) {
    atomicAdd(&acc[0], r0[0] + r0[1] + r0[2] + r0[3]);
    atomicAdd(&acc[1], r1[0] + r1[1] + r1[2] + r1[3]);
    __threadfence();
    const int done = atomicAdd(ticket, 1);
    if (done == 63) {   // last block: fold final loss (atomic reads only)
      const float a0v = atomicAdd(&acc[0], 0.0f);
      const float a1v = atomicAdd(&acc[1], 0.0f);
      float l = 0.f;
      if (valid[0] > 0) l += a0v / (float)(BATCH * valid[0]);
      if (valid[1] > 0) l += a1v / (float)(BATCH * valid[1]);
      lossp[0] = l;
    }
  }
}

extern "C" void kernel_launch(void* const* d_in, const int* in_sizes, int n_in,
                              void* d_out, int out_size, void* d_ws,
                              size_t ws_size, hipStream_t stream) {
  const float* x0 = (const float*)d_in[0];
  const float* x1 = (const float*)d_in[1];
  const float* w0 = (const float*)d_in[2];
  const float* w1 = (const float*)d_in[3];
  const float* ehy0 = (const float*)d_in[4];
  const float* ehy1 = (const float*)d_in[5];
  const float* enod0 = (const float*)d_in[6];
  const float* enod1 = (const float*)d_in[7];

  float* out = (float*)d_out;
  float* adj0 = out;                       // 640*128
  float* adj1 = out + 640 * 128;           // 384*64
  float* lossp = out + 640 * 128 + 384 * 64;

  unsigned short* nhat0 = (unsigned short*)d_ws;
  unsigned short* nhat1 = nhat0 + (size_t)BATCH * 640 * DDIM;
  int* ip = (int*)(nhat1 + (size_t)BATCH * 384 * DDIM);
  int* labels0 = ip;
  int* labels1 = labels0 + 640;
  int* cnt0 = labels1 + 384;
  int* cnt1 = cnt0 + 640;
  int* valid = cnt1 + 384;
  int* ticket = valid + 2;
  float* acc = (float*)(ticket + 1);
  float2* sp = (float2*)((((size_t)(acc + 2)) + 255) & ~(size_t)255);
  // sp: 10 slots x 65536 gids x 8 B = 5.24 MB (ws total ~72.4 MB)

  prep_kernel<<<1024 + 16384, 256, 0, stream>>>(
      enod0, ehy0, enod1, ehy1, adj0, adj1, labels0, labels1,
      x0, w0, x1, w1, nhat0, nhat1, acc, ticket);
  cnt_kernel<<<2, 256, 0, stream>>>(labels0, cnt0, labels1, cnt1, valid);
  lse_kernel<<<1024, 128, 0, stream>>>(nhat0, labels0, nhat1, labels1, sp);
  loss_reduce<<<64, 256, 0, stream>>>(sp, cnt0, cnt1, acc, valid, ticket,
                                      lossp);
}

// Round 5
// 245.092 us; speedup vs baseline: 1.0731x; 1.0292x over previous
//
#include <hip/hip_runtime.h>

// incidence_matrix_learn on MI355X — round 13.
// r10/r11/r12 post-mortem: every 2-wave variant lands at 86-92us with real
// VMEM delivery ~10.7 B/cyc/CU (half of m97's 22), FETCH shows A re-sunk
// every round (allocator refuses >128 VGPR; "+v" pins ineffective, no spill
// traffic in WRITE_SIZE). Fix the SHAPE instead of fighting the allocator:
// 8-wave blocks, wave owns 16 u-rows -> A = 64 VGPRs (fits 128 by design,
// enforced via __launch_bounds__(512,4)); block = 128-row u-band so each
// staged B-chunk feeds 8 waves (FLOP/staged-byte 64 -> 128); 16KB chunks
// (64m x 128k, ring-3, vmcnt(2)) halve barrier rate per byte. Band-pair
// symmetry: intra-band tiles supply each other's cross row-sums (no col
// harvest, zero waste); tv>=2bu+2 tiles harvest rows + 8-wave col-sums.
// Grid: 8 LPT-sorted band-classes x 2 stride-2 halves x 64 batches = 1024
// uniform-ish blocks, heavy first, batch in low bits (XCD-pinned).
// Staged bytes ~306MB (vs ~600 real in r12).
// Validated algebra (rounds 1-12, absmax 0.0): top-k no-op; P via labels;
// fixed-shift-10 LSE (denom INCLUDES self; pos excludes); bf16 nhat;
// cnt = label-histogram - 1; counted-vmcnt ring staging; disjoint sp slots.

#define DDIM 512
#define BATCH 64
#define NGID 65536   // 64*640 + 64*384 node-row slots across both scales
#define NSLOT 6      // slots 0,1 = half rows; 2+bu = col partials (bu<=3)

typedef __attribute__((ext_vector_type(8))) short short8;
typedef __attribute__((ext_vector_type(4))) float f32x4;

// Band classes sorted by half-sweep length (LPT): {scale, bu, tiles/half}.
__constant__ int CLS_SCALE[8] = {0, 0, 0, 1, 0, 1, 0, 1};
__constant__ int CLS_BU[8]    = {0, 1, 2, 0, 3, 1, 4, 2};
__constant__ int CLS_NTL[8]   = {5, 4, 3, 3, 2, 2, 1, 1};

__device__ __forceinline__ unsigned short f2bf(float f) {
  unsigned int u = __float_as_uint(f);
  u += 0x7fffu + ((u >> 16) & 1u);   // RNE
  return (unsigned short)(u >> 16);
}

__device__ __forceinline__ void async16(const void* g, void* l) {
  __builtin_amdgcn_global_load_lds(
      (const __attribute__((address_space(1))) unsigned int*)g,
      (__attribute__((address_space(3))) unsigned int*)l, 16, 0, 0);
}

__device__ __forceinline__ int m3(int x) {  // x in [0, 12): x mod 3
  x -= (x >= 6) ? 6 : 0;
  x -= (x >= 3) ? 3 : 0;
  return x;
}

// Fused prep kernel, 256 threads. Blocks [0,1024): adj (both scales) + acc/
// ticket init. Blocks [1024, 1024+16384): normalize, one WAVE per node row.
__global__ __launch_bounds__(256) void prep_kernel(
    const float* __restrict__ enod0, const float* __restrict__ ehy0,
    const float* __restrict__ enod1, const float* __restrict__ ehy1,
    float* __restrict__ adj0, float* __restrict__ adj1,
    int* __restrict__ labels0, int* __restrict__ labels1,
    const float* __restrict__ x0, const float* __restrict__ w0,
    const float* __restrict__ x1, const float* __restrict__ w1,
    unsigned short* __restrict__ nhat0, unsigned short* __restrict__ nhat1,
    float* __restrict__ acc, int* __restrict__ ticket) {
  const int t = threadIdx.x;
  if (blockIdx.x < 1024) {
    // ---- adj path ----
    if (blockIdx.x == 0 && t == 0) { acc[0] = 0.f; acc[1] = 0.f; ticket[0] = 0; }
    const bool s0 = blockIdx.x < 640;
    const int n = s0 ? blockIdx.x : blockIdx.x - 640;
    const int H = s0 ? 128 : 64;
    const float* enod = s0 ? enod0 : enod1;
    const float* ehy = s0 ? ehy0 : ehy1;
    float* out_adj = s0 ? adj0 : adj1;
    int* labels = s0 ? labels0 : labels1;
    __shared__ float erow[DDIM];
    __shared__ float red[128];
    __shared__ int lab;
    if (t < 128) ((float4*)erow)[t] = ((const float4*)(enod + (size_t)n * DDIM))[t];
    if (t == 0) lab = -1;
    __syncthreads();
    float v = 0.f;
    if (t < H) {
      const float4* hr = (const float4*)(ehy + (size_t)t * DDIM);
      float a = 0.f;
      #pragma unroll 8
      for (int d = 0; d < DDIM / 4; ++d) {
        float4 h = hr[d];
        float4 e = ((const float4*)erow)[d];
        a = fmaf(h.x, e.x, a); a = fmaf(h.y, e.y, a);
        a = fmaf(h.z, e.z, a); a = fmaf(h.w, e.w, a);
      }
      v = fmaxf(0.f, 3.0f * a);
    }
    if (t < 128) red[t] = v;
    __syncthreads();
    for (int s = 64; s > 0; s >>= 1) {
      if (t < s) red[t] = fmaxf(red[t], red[t + s]);
      __syncthreads();
    }
    const float mx = red[0];
    __syncthreads();
    const float e = (t < H) ? __expf(v - mx) : 0.f;
    if (t < 128) red[t] = e;
    __syncthreads();
    for (int s = 64; s > 0; s >>= 1) {
      if (t < s) red[t] += red[t + s];
      __syncthreads();
    }
    const float sum = red[0];
    if (t < H) {
      const float adj = e / sum;
      const float bin = (adj > 0.5f) ? 1.0f : 0.0f;
      out_adj[(size_t)n * H + t] = bin;
      if (bin > 0.f) lab = t;
    }
    __syncthreads();
    if (t == 0) labels[n] = lab;
  } else {
    // ---- normalize path: wave per row ----
    const int wave = t >> 6;
    const int lane = t & 63;
    const int g = (blockIdx.x - 1024) * 4 + wave;   // global row id, < 65536
    const bool s0 = g < BATCH * 640;
    const int gg = s0 ? g : g - BATCH * 640;
    const int N = s0 ? 640 : 384;
    const int L = s0 ? 512 : 256;
    const float* x = s0 ? x0 : x1;
    const float* w = s0 ? w0 : w1;
    unsigned short* nhat = s0 ? nhat0 : nhat1;
    const int b = gg / N;
    const int n = gg - b * N;
    const float* src = (n < L) ? (x + ((size_t)b * L + n) * DDIM)
                               : (w + (size_t)(n - L) * DDIM);
    const float4* rowp = (const float4*)src;
    const float4 v0 = rowp[lane];
    const float4 v1 = rowp[lane + 64];
    float ss = v0.x * v0.x + v0.y * v0.y + v0.z * v0.z + v0.w * v0.w +
               v1.x * v1.x + v1.y * v1.y + v1.z * v1.z + v1.w * v1.w;
    #pragma unroll
    for (int off = 32; off > 0; off >>= 1) ss += __shfl_xor(ss, off);
    const float rinv = 1.0f / fmaxf(sqrtf(ss), 1e-12f);
    ushort4 o0, o1;
    o0.x = f2bf(v0.x * rinv); o0.y = f2bf(v0.y * rinv);
    o0.z = f2bf(v0.z * rinv); o0.w = f2bf(v0.w * rinv);
    o1.x = f2bf(v1.x * rinv); o1.y = f2bf(v1.y * rinv);
    o1.z = f2bf(v1.z * rinv); o1.w = f2bf(v1.w * rinv);
    ushort4* op = (ushort4*)(nhat + ((size_t)b * N + n) * DDIM);
    op[lane] = o0;
    op[lane + 64] = o1;
  }
}

// 2 blocks. cnt[i] = hist[lab[i]] - 1 via 128-bin LDS label histogram.
__global__ __launch_bounds__(256) void cnt_kernel(
    const int* __restrict__ labels0, int* __restrict__ cnt0,
    const int* __restrict__ labels1, int* __restrict__ cnt1,
    int* __restrict__ valid) {
  const bool s0 = blockIdx.x == 0;
  const int* labels = s0 ? labels0 : labels1;
  int* cnt = s0 ? cnt0 : cnt1;
  int* validcnt = s0 ? valid : valid + 1;
  const int N = s0 ? 640 : 384;
  __shared__ int lab[640];
  __shared__ int hist[128];
  __shared__ int vc;
  const int t = threadIdx.x;
  if (t == 0) vc = 0;
  if (t < 128) hist[t] = 0;
  for (int i = t; i < N; i += 256) lab[i] = labels[i];
  __syncthreads();
  for (int i = t; i < N; i += 256)
    if (lab[i] >= 0) atomicAdd(&hist[lab[i]], 1);
  __syncthreads();
  int lv = 0;
  for (int i = t; i < N; i += 256) {
    const int c = (lab[i] >= 0) ? hist[lab[i]] - 1 : 0;
    cnt[i] = c;
    if (c > 0) ++lv;
  }
  if (lv > 0) atomicAdd(&vc, lv);
  __syncthreads();
  if (t == 0) *validcnt = vc;
}

// Band-sweep MFMA lse kernel, 512 threads (8 waves) per (class, half, b).
// Wave owns 16 u-rows (A = 16 short8 frags = 64 VGPRs, resident by design).
// Block owns a 128-row u-band (2 u-tiles), sweeps tv = 2bu+half, +2, ... as
// a continuous 16KB-chunk stream (64m x 128k, ring-3, counted vmcnt(2)).
// Harvest per tile: rows always (diag tiles self-excluded; the two intra-
// band tiles supply each other's cross terms, no col needed); col-sums only
// for tv >= 2bu+2 (8-wave LDS combine -> slot 2+bu). Row-sums accumulate in
// regs across the sweep -> slot `half`.
__global__ __launch_bounds__(512, 4) void lse_kernel(
    const unsigned short* __restrict__ nhat0, const int* __restrict__ labels0,
    const unsigned short* __restrict__ nhat1, const int* __restrict__ labels1,
    float2* __restrict__ sp) {
  __shared__ short8 Bbuf[3][1024];   // ring-3 x 16 KB, frag-order
  __shared__ float2 redC[8][64];     // 8-wave col-sum combine
  __shared__ int labS[640];
  const int tid = threadIdx.x;
  const int cls = blockIdx.x >> 7;
  const int half = (blockIdx.x >> 6) & 1;
  const int b = blockIdx.x & 63;     // batch in low bits: XCD-pinned
  const bool s0 = CLS_SCALE[cls] == 0;
  const int bu = CLS_BU[cls];
  const int ntl = CLS_NTL[cls];      // tiles in this half-sweep
  const int N = s0 ? 640 : 384;
  const unsigned short* nhat = s0 ? nhat0 : nhat1;
  const int* labels = s0 ? labels0 : labels1;
  const int gbase = s0 ? b * 640 : 40960 + b * 384;

  const int w = tid >> 6;       // wave 0..7
  const int lane = tid & 63;
  const int lrow = lane & 15;   // A-row within 16 / B-col / C-col
  const int lq = lane >> 4;     // k-slot selector / C row group
  const int wq = w & 3;         // u-tile-local 16-row group
  const int ut = 2 * bu + (w >> 2);   // this wave's u-tile (64-granularity)

  for (int t = tid; t < N; t += 512) labS[t] = labels[t];

  const size_t base = (size_t)b * N * DDIM;
  const int bandrow0 = bu * 128;
  const int myrow = bandrow0 + w * 16 + lrow;   // this lane's A row
  const unsigned short* Ap = nhat + base + (size_t)myrow * DDIM + lq * 8;
  short8 a[16];
  #pragma unroll
  for (int ki = 0; ki < 16; ++ki) a[ki] = *(const short8*)(Ap + ki * 32);

  __syncthreads();   // labS visible; full vmcnt drain: ring counting clean

  int labn[4];
  #pragma unroll
  for (int r = 0; r < 4; ++r)
    labn[r] = labS[bandrow0 + w * 16 + lq * 4 + r];

  // prologue: chunks 0,1 of the first tile (2 frags per wave per chunk)
  const int tv0 = 2 * bu + half;
  const unsigned short* Bp0 = nhat + base + (size_t)tv0 * 64 * DDIM;
  const int f0 = w * 2;
  #pragma unroll
  for (int pc = 0; pc < 2; ++pc) {
    #pragma unroll
    for (int fi = 0; fi < 2; ++fi) {
      const int f = f0 + fi, j = f >> 2, ks = f & 3;
      async16(Bp0 + (size_t)(j * 16 + lrow) * DDIM + pc * 128 + ks * 32 + lq * 8,
              &Bbuf[pc][f * 64]);
    }
  }

  float rSE[4] = {0.f, 0.f, 0.f, 0.f};
  float rPOS[4] = {0.f, 0.f, 0.f, 0.f};
  int slotb = 0;   // ring slot of kc=0 for the current tile

  for (int ti = 0; ti < ntl; ++ti) {
    const int tv = tv0 + 2 * ti;
    const bool last = (ti == ntl - 1);
    const unsigned short* Bcur = nhat + base + (size_t)tv * 64 * DDIM;
    const unsigned short* Bnxt = Bcur + (size_t)128 * DDIM;  // next tile: tv+2
    const int sl[3] = {slotb, m3(slotb + 1), m3(slotb + 2)};

    f32x4 acc[4];
    #pragma unroll
    for (int j = 0; j < 4; ++j) acc[j] = (f32x4){0.f, 0.f, 0.f, 0.f};

    #pragma unroll
    for (int kc = 0; kc < 4; ++kc) {
      // own 2 loads of this chunk done; next chunk's 2 (and maybe a col
      // store) stay in flight. Over-waits are harmless.
      if (last && kc == 3) asm volatile("s_waitcnt vmcnt(0)" ::: "memory");
      else                 asm volatile("s_waitcnt vmcnt(2)" ::: "memory");
      __builtin_amdgcn_s_barrier();   // all waves' chunk loads landed;
                                      // readers of slot being refilled done
      if (!(last && kc >= 2)) {
        const unsigned short* Bsrc = (kc < 2) ? Bcur : Bnxt;
        const int kcol = (kc + 2) & 3;
        short8* dst = &Bbuf[sl[(kc + 2) % 3]][0];
        #pragma unroll
        for (int fi = 0; fi < 2; ++fi) {
          const int f = f0 + fi, j = f >> 2, ks = f & 3;
          async16(Bsrc + (size_t)(j * 16 + lrow) * DDIM + kcol * 128 + ks * 32 + lq * 8,
                  dst + f * 64);
        }
      }
      const short8* bb = &Bbuf[sl[kc % 3]][0];
      #pragma unroll
      for (int ks = 0; ks < 4; ++ks) {
        const short8 b0 = bb[(0 * 4 + ks) * 64 + lane];
        const short8 b1 = bb[(1 * 4 + ks) * 64 + lane];
        const short8 b2 = bb[(2 * 4 + ks) * 64 + lane];
        const short8 b3 = bb[(3 * 4 + ks) * 64 + lane];
        const short8 av = a[kc * 4 + ks];
        acc[0] = __builtin_amdgcn_mfma_f32_16x16x32_bf16(av, b0, acc[0], 0, 0, 0);
        acc[1] = __builtin_amdgcn_mfma_f32_16x16x32_bf16(av, b1, acc[1], 0, 0, 0);
        acc[2] = __builtin_amdgcn_mfma_f32_16x16x32_bf16(av, b2, acc[2], 0, 0, 0);
        acc[3] = __builtin_amdgcn_mfma_f32_16x16x32_bf16(av, b3, acc[3], 0, 0, 0);
      }
    }

    // harvest tile tv
    const bool diag = (ut == tv);
    const bool colp = (tv >= 2 * bu + 2);
    float cSE[4] = {0.f, 0.f, 0.f, 0.f};
    float cPOS[4] = {0.f, 0.f, 0.f, 0.f};
    #pragma unroll
    for (int j = 0; j < 4; ++j) {
      const int v = tv * 64 + j * 16 + lrow;
      const int labm = labS[v];
      #pragma unroll
      for (int r = 0; r < 4; ++r) {
        const float sim = acc[j][r] * 10.0f;       // 1/TAU
        const float e = __expf(sim - 10.0f);       // fixed shift (diag max)
        rSE[r] += e;                                // denom includes self
        const bool match = (labn[r] >= 0) && (labm == labn[r]);
        const bool self = diag && (j == wq) && (lrow == lq * 4 + r);
        if (match && !self) rPOS[r] += sim;
        if (colp) {
          cSE[j] += e;
          if (match) cPOS[j] += sim;   // cross-tile: self impossible
        }
      }
    }
    if (colp) {
      // col reduce across lq groups (lanes ^16, ^32)
      #pragma unroll
      for (int off = 16; off <= 32; off <<= 1) {
        #pragma unroll
        for (int j = 0; j < 4; ++j) {
          cSE[j] += __shfl_xor(cSE[j], off);
          cPOS[j] += __shfl_xor(cPOS[j], off);
        }
      }
      if (lane < 16) {
        #pragma unroll
        for (int j = 0; j < 4; ++j) {
          float2 st; st.x = cSE[j]; st.y = cPOS[j];
          redC[w][j * 16 + lane] = st;
        }
      }
      // 8-wave combine WITHOUT draining vmcnt (prefetches in flight):
      asm volatile("s_waitcnt lgkmcnt(0)" ::: "memory");
      __builtin_amdgcn_s_barrier();
      if (tid < 64) {
        float se = 0.f, ps = 0.f;
        #pragma unroll
        for (int ww = 0; ww < 8; ++ww) {
          const float2 c = redC[ww][tid];
          se += c.x; ps += c.y;
        }
        float2 st; st.x = se; st.y = ps;
        sp[(size_t)(2 + bu) * NGID + gbase + tv * 64 + tid] = st;
      }
      // redC reuse next tile is separated by the next chunk-top barrier
    }
    slotb = m3(slotb + 1);   // 4 chunks advance ring by 4 mod 3 = 1
  }

  // row reduce across the 16 col-lanes, store slot `half`
  #pragma unroll
  for (int off = 1; off <= 8; off <<= 1) {
    #pragma unroll
    for (int r = 0; r < 4; ++r) {
      rSE[r] += __shfl_xor(rSE[r], off);
      rPOS[r] += __shfl_xor(rPOS[r], off);
    }
  }
  if (lrow == 0) {
    #pragma unroll
    for (int r = 0; r < 4; ++r) {
      const int u = bandrow0 + w * 16 + lq * 4 + r;
      float2 st; st.x = rSE[r]; st.y = rPOS[r];
      sp[(size_t)half * NGID + gbase + u] = st;
    }
  }
}

// Sum per-gid partials over slots {0,1} + col slots 2..2+(t>>1)-1, apply
// LSE + pos/cnt, reduce. Last block (ticket) folds the final loss scalar.
__global__ __launch_bounds__(256) void loss_reduce(
    const float2* __restrict__ sp, const int* __restrict__ cnt0,
    const int* __restrict__ cnt1, float* __restrict__ acc,
    const int* __restrict__ valid, int* __restrict__ ticket,
    float* __restrict__ lossp) {
  __shared__ float r0[4], r1[4];
  const int t = threadIdx.x;
  float l0 = 0.f, l1 = 0.f;
  for (int g = blockIdx.x * 256 + t; g < NGID; g += 64 * 256) {
    const bool is0 = g < 40960;
    const int n = is0 ? (g % 640) : ((g - 40960) % 384);
    const int tt = n >> 6;
    const int nslots = 2 + (tt >> 1);
    float se = 0.f, pos = 0.f;
    for (int s = 0; s < nslots; ++s) {
      const float2 v = sp[(size_t)s * NGID + g];
      se += v.x; pos += v.y;
    }
    const int c = is0 ? cnt0[n] : cnt1[n];
    if (c > 0) {
      const float v = (10.0f + logf(se)) - pos / (float)c;
      if (is0) l0 += v; else l1 += v;
    }
  }
  #pragma unroll
  for (int off = 32; off > 0; off >>= 1) {
    l0 += __shfl_xor(l0, off);
    l1 += __shfl_xor(l1, off);
  }
  if ((t & 63) == 0) { r0[t >> 6] = l0; r1[t >> 6] = l1; }
  __syncthreads();
  if (t == 0) {
    atomicAdd(&acc[0], r0[0] + r0[1] + r0[2] + r0[3]);
    atomicAdd(&acc[1], r1[0] + r1[1] + r1[2] + r1[3]);
    __threadfence();
    const int done = atomicAdd(ticket, 1);
    if (done == 63) {   // last block: fold final loss (atomic reads only)
      const float a0v = atomicAdd(&acc[0], 0.0f);
      const float a1v = atomicAdd(&acc[1], 0.0f);
      float l = 0.f;
      if (valid[0] > 0) l += a0v / (float)(BATCH * valid[0]);
      if (valid[1] > 0) l += a1v / (float)(BATCH * valid[1]);
      lossp[0] = l;
    }
  }
}

extern "C" void kernel_launch(void* const* d_in, const int* in_sizes, int n_in,
                              void* d_out, int out_size, void* d_ws,
                              size_t ws_size, hipStream_t stream) {
  const float* x0 = (const float*)d_in[0];
  const float* x1 = (const float*)d_in[1];
  const float* w0 = (const float*)d_in[2];
  const float* w1 = (const float*)d_in[3];
  const float* ehy0 = (const float*)d_in[4];
  const float* ehy1 = (const float*)d_in[5];
  const float* enod0 = (const float*)d_in[6];
  const float* enod1 = (const float*)d_in[7];

  float* out = (float*)d_out;
  float* adj0 = out;                       // 640*128
  float* adj1 = out + 640 * 128;           // 384*64
  float* lossp = out + 640 * 128 + 384 * 64;

  unsigned short* nhat0 = (unsigned short*)d_ws;
  unsigned short* nhat1 = nhat0 + (size_t)BATCH * 640 * DDIM;
  int* ip = (int*)(nhat1 + (size_t)BATCH * 384 * DDIM);
  int* labels0 = ip;
  int* labels1 = labels0 + 640;
  int* cnt0 = labels1 + 384;
  int* cnt1 = cnt0 + 640;
  int* valid = cnt1 + 384;
  int* ticket = valid + 2;
  float* acc = (float*)(ticket + 1);
  float2* sp = (float2*)((((size_t)(acc + 2)) + 255) & ~(size_t)255);
  // sp: 6 slots x 65536 gids x 8 B = 3.1 MB (ws total ~70 MB)

  prep_kernel<<<1024 + 16384, 256, 0, stream>>>(
      enod0, ehy0, enod1, ehy1, adj0, adj1, labels0, labels1,
      x0, w0, x1, w1, nhat0, nhat1, acc, ticket);
  cnt_kernel<<<2, 256, 0, stream>>>(labels0, cnt0, labels1, cnt1, valid);
  lse_kernel<<<1024, 512, 0, stream>>>(nhat0, labels0, nhat1, labels1, sp);
  loss_reduce<<<64, 256, 0, stream>>>(sp, cnt0, cnt1, acc, valid, ticket,
                                      lossp);
}

// Round 7
// 234.962 us; speedup vs baseline: 1.1194x; 1.0431x over previous
//
#include <hip/hip_runtime.h>

// incidence_matrix_learn on MI355X — round 15 (= round 14 + 1-line fix).
// Round-14 bench never ran (container failure, no counters). Audit found one
// latent bug: STAGE passed a PER-LANE LDS destination to global_load_lds.
// HW semantics (m104/m108): dst is wave-uniform base + lane*16; rounds 8-13
// always passed the uniform base. Fixed: dst = &buf[f*64] (uniform); lane i
// lands at f*64+lane automatically — exactly the frag layout MFMA reads.
// Structure (round-14 rationale): r13 showed VGPR_Count=64 + 63MB spill ->
// hipcc will not keep a long-lived A-panel in VGPRs across a runtime loop
// (r9-r12: re-loads; r13: spills). m97 structure instead: BOTH panels staged
// per-K-step into double-buffered LDS via global_load_lds, plain
// __syncthreads, only acc in registers.
// lse = triangular tile-pair GEMM: 128x128 tiles, BK=64, 4 waves (2x2),
// 2x(16+16)KB LDS dbuf, 8-step K-loop. 640=5x128, 384=3x128 -> 15+6=21
// pairs x 64 batches = 1344 uniform blocks (batch in low bits = XCD-pinned;
// per-XCD panels ~2MB = L2-resident). Rows -> slot tv, cols (off-diag) ->
// slot tu; every slot written exactly once, non-atomic.
// Arithmetic: MFMA 22.6GF@~900TF ~ 25us; staged 344MB@22B/cyc/CU ~ 25us;
// LDS-read 688MB ~ 26us -> overlapped ~35-45us (r13 was 81).
// Validated algebra (rounds 1-13, absmax 0.0): top-k no-op; P via labels;
// fixed-shift-10 LSE (denom includes self; pos excludes); bf16 nhat;
// cnt = label-histogram - 1; disjoint sp slots; frag-order LDS staging.

#define DDIM 512
#define BATCH 64
#define NGID 65536   // 64*640 + 64*384 node-row slots across both scales
#define NSLOT 5      // 128-granularity bands: scale0 uses 5, scale1 uses 3

typedef __attribute__((ext_vector_type(8))) short short8;
typedef __attribute__((ext_vector_type(4))) float f32x4;

// Triangular tile-pair list (128-granularity): 15 scale0 + 6 scale1.
__constant__ int PAIR_SCALE[21] = {0,0,0,0,0,0,0,0,0,0,0,0,0,0,0, 1,1,1,1,1,1};
__constant__ int PAIR_TU[21]    = {0,0,0,0,0,1,1,1,1,2,2,2,3,3,4, 0,0,0,1,1,2};
__constant__ int PAIR_TV[21]    = {0,1,2,3,4,1,2,3,4,2,3,4,3,4,4, 0,1,2,1,2,2};

__device__ __forceinline__ unsigned short f2bf(float f) {
  unsigned int u = __float_as_uint(f);
  u += 0x7fffu + ((u >> 16) & 1u);   // RNE
  return (unsigned short)(u >> 16);
}

__device__ __forceinline__ void async16(const void* g, void* l) {
  __builtin_amdgcn_global_load_lds(
      (const __attribute__((address_space(1))) unsigned int*)g,
      (__attribute__((address_space(3))) unsigned int*)l, 16, 0, 0);
}

// Fused prep kernel, 256 threads. Blocks [0,1024): adj (both scales) + acc/
// ticket init. Blocks [1024, 1024+16384): normalize, one WAVE per node row.
__global__ __launch_bounds__(256) void prep_kernel(
    const float* __restrict__ enod0, const float* __restrict__ ehy0,
    const float* __restrict__ enod1, const float* __restrict__ ehy1,
    float* __restrict__ adj0, float* __restrict__ adj1,
    int* __restrict__ labels0, int* __restrict__ labels1,
    const float* __restrict__ x0, const float* __restrict__ w0,
    const float* __restrict__ x1, const float* __restrict__ w1,
    unsigned short* __restrict__ nhat0, unsigned short* __restrict__ nhat1,
    float* __restrict__ acc, int* __restrict__ ticket) {
  const int t = threadIdx.x;
  if (blockIdx.x < 1024) {
    // ---- adj path ----
    if (blockIdx.x == 0 && t == 0) { acc[0] = 0.f; acc[1] = 0.f; ticket[0] = 0; }
    const bool s0 = blockIdx.x < 640;
    const int n = s0 ? blockIdx.x : blockIdx.x - 640;
    const int H = s0 ? 128 : 64;
    const float* enod = s0 ? enod0 : enod1;
    const float* ehy = s0 ? ehy0 : ehy1;
    float* out_adj = s0 ? adj0 : adj1;
    int* labels = s0 ? labels0 : labels1;
    __shared__ float erow[DDIM];
    __shared__ float red[128];
    __shared__ int lab;
    if (t < 128) ((float4*)erow)[t] = ((const float4*)(enod + (size_t)n * DDIM))[t];
    if (t == 0) lab = -1;
    __syncthreads();
    float v = 0.f;
    if (t < H) {
      const float4* hr = (const float4*)(ehy + (size_t)t * DDIM);
      float a = 0.f;
      #pragma unroll 8
      for (int d = 0; d < DDIM / 4; ++d) {
        float4 h = hr[d];
        float4 e = ((const float4*)erow)[d];
        a = fmaf(h.x, e.x, a); a = fmaf(h.y, e.y, a);
        a = fmaf(h.z, e.z, a); a = fmaf(h.w, e.w, a);
      }
      v = fmaxf(0.f, 3.0f * a);
    }
    if (t < 128) red[t] = v;
    __syncthreads();
    for (int s = 64; s > 0; s >>= 1) {
      if (t < s) red[t] = fmaxf(red[t], red[t + s]);
      __syncthreads();
    }
    const float mx = red[0];
    __syncthreads();
    const float e = (t < H) ? __expf(v - mx) : 0.f;
    if (t < 128) red[t] = e;
    __syncthreads();
    for (int s = 64; s > 0; s >>= 1) {
      if (t < s) red[t] += red[t + s];
      __syncthreads();
    }
    const float sum = red[0];
    if (t < H) {
      const float adj = e / sum;
      const float bin = (adj > 0.5f) ? 1.0f : 0.0f;
      out_adj[(size_t)n * H + t] = bin;
      if (bin > 0.f) lab = t;
    }
    __syncthreads();
    if (t == 0) labels[n] = lab;
  } else {
    // ---- normalize path: wave per row ----
    const int wave = t >> 6;
    const int lane = t & 63;
    const int g = (blockIdx.x - 1024) * 4 + wave;   // global row id, < 65536
    const bool s0 = g < BATCH * 640;
    const int gg = s0 ? g : g - BATCH * 640;
    const int N = s0 ? 640 : 384;
    const int L = s0 ? 512 : 256;
    const float* x = s0 ? x0 : x1;
    const float* w = s0 ? w0 : w1;
    unsigned short* nhat = s0 ? nhat0 : nhat1;
    const int b = gg / N;
    const int n = gg - b * N;
    const float* src = (n < L) ? (x + ((size_t)b * L + n) * DDIM)
                               : (w + (size_t)(n - L) * DDIM);
    const float4* rowp = (const float4*)src;
    const float4 v0 = rowp[lane];
    const float4 v1 = rowp[lane + 64];
    float ss = v0.x * v0.x + v0.y * v0.y + v0.z * v0.z + v0.w * v0.w +
               v1.x * v1.x + v1.y * v1.y + v1.z * v1.z + v1.w * v1.w;
    #pragma unroll
    for (int off = 32; off > 0; off >>= 1) ss += __shfl_xor(ss, off);
    const float rinv = 1.0f / fmaxf(sqrtf(ss), 1e-12f);
    ushort4 o0, o1;
    o0.x = f2bf(v0.x * rinv); o0.y = f2bf(v0.y * rinv);
    o0.z = f2bf(v0.z * rinv); o0.w = f2bf(v0.w * rinv);
    o1.x = f2bf(v1.x * rinv); o1.y = f2bf(v1.y * rinv);
    o1.z = f2bf(v1.z * rinv); o1.w = f2bf(v1.w * rinv);
    ushort4* op = (ushort4*)(nhat + ((size_t)b * N + n) * DDIM);
    op[lane] = o0;
    op[lane + 64] = o1;
  }
}

// 2 blocks. cnt[i] = hist[lab[i]] - 1 via 128-bin LDS label histogram.
__global__ __launch_bounds__(256) void cnt_kernel(
    const int* __restrict__ labels0, int* __restrict__ cnt0,
    const int* __restrict__ labels1, int* __restrict__ cnt1,
    int* __restrict__ valid) {
  const bool s0 = blockIdx.x == 0;
  const int* labels = s0 ? labels0 : labels1;
  int* cnt = s0 ? cnt0 : cnt1;
  int* validcnt = s0 ? valid : valid + 1;
  const int N = s0 ? 640 : 384;
  __shared__ int lab[640];
  __shared__ int hist[128];
  __shared__ int vc;
  const int t = threadIdx.x;
  if (t == 0) vc = 0;
  if (t < 128) hist[t] = 0;
  for (int i = t; i < N; i += 256) lab[i] = labels[i];
  __syncthreads();
  for (int i = t; i < N; i += 256)
    if (lab[i] >= 0) atomicAdd(&hist[lab[i]], 1);
  __syncthreads();
  int lv = 0;
  for (int i = t; i < N; i += 256) {
    const int c = (lab[i] >= 0) ? hist[lab[i]] - 1 : 0;
    cnt[i] = c;
    if (c > 0) ++lv;
  }
  if (lv > 0) atomicAdd(&vc, lv);
  __syncthreads();
  if (t == 0) *validcnt = vc;
}

// m97-style triangular GEMM lse kernel: 256 threads (4 waves, 2x2), one
// (pair, batch) 128x128 tile per block. A/B panels staged per-64-K-step
// into double-buffered frag-order LDS via global_load_lds; only acc lives
// in registers. Plain __syncthreads (m97-verified schedule).
__global__ __launch_bounds__(256) void lse_kernel(
    const unsigned short* __restrict__ nhat0, const int* __restrict__ labels0,
    const unsigned short* __restrict__ nhat1, const int* __restrict__ labels1,
    float2* __restrict__ sp) {
  __shared__ short8 Abuf[2][1024];   // 2 x 16 KB, frag-order
  __shared__ short8 Bbuf[2][1024];
  __shared__ int labU[128], labV[128];
  __shared__ float2 rowBuf[128][2];  // [row][wc]
  __shared__ float2 colBuf[128][2];  // [col][wr]

  const int tid = threadIdx.x;
  const int p = blockIdx.x >> 6;
  const int b = blockIdx.x & 63;     // batch in low bits: XCD-pinned
  const bool s0 = PAIR_SCALE[p] == 0;
  const int tu = PAIR_TU[p], tv = PAIR_TV[p];
  const bool diag = (tu == tv);
  const int N = s0 ? 640 : 384;
  const unsigned short* nhat = s0 ? nhat0 : nhat1;
  const int* labels = s0 ? labels0 : labels1;
  const int gbase = s0 ? b * 640 : 40960 + b * 384;
  const size_t base = (size_t)b * N * DDIM;

  const int w = tid >> 6, lane = tid & 63;
  const int wr = w >> 1, wc = w & 1;
  const int lrow = lane & 15, lq = lane >> 4;

  if (tid < 128) labU[tid] = labels[tu * 128 + tid];
  else labV[tid - 128] = labels[tv * 128 + (tid - 128)];

  const unsigned short* Asrc = nhat + base + (size_t)tu * 128 * DDIM;
  const unsigned short* Bsrc = nhat + base + (size_t)tv * 128 * DDIM;

  // Stage one 64-K slab of both panels into buffer `buf`, frag-order.
  // Per wave w, issue i: frag f = i*4+w. LDS dst is the WAVE-UNIFORM base
  // &buf[f*64]; HW places lane i's 16 B at +i*16 (m104/m108), i.e. element
  // f*64+lane — exactly the MFMA frag layout read below. Global src is
  // per-lane: row = rg*16+lrow, k = kk*64 + ks*32 + lq*8.
  #define STAGE(buf, kk)                                                     \
    do {                                                                     \
      _Pragma("unroll")                                                      \
      for (int i = 0; i < 4; ++i) {                                          \
        const int f = i * 4 + w;                                             \
        const int rg = f >> 1, ks = f & 1;                                   \
        const size_t so = (size_t)(rg * 16 + lrow) * DDIM +                  \
                          (kk) * 64 + ks * 32 + lq * 8;                      \
        async16(Asrc + so, &Abuf[buf][f * 64]);                              \
        async16(Bsrc + so, &Bbuf[buf][f * 64]);                              \
      }                                                                      \
    } while (0)

  f32x4 acc[4][4];
  #pragma unroll
  for (int mi = 0; mi < 4; ++mi)
    #pragma unroll
    for (int ni = 0; ni < 4; ++ni) acc[mi][ni] = (f32x4){0.f, 0.f, 0.f, 0.f};

  STAGE(0, 0);
  __syncthreads();   // stage 0 landed (vmcnt drained by barrier semantics)

  for (int k = 0; k < 8; ++k) {
    const int cur = k & 1;
    if (k < 7) STAGE(cur ^ 1, k + 1);   // prefetch next slab, other buffer
    #pragma unroll
    for (int ks = 0; ks < 2; ++ks) {
      short8 am[4], bn[4];
      #pragma unroll
      for (int mi = 0; mi < 4; ++mi)
        am[mi] = Abuf[cur][((wr * 4 + mi) * 2 + ks) * 64 + lane];
      #pragma unroll
      for (int ni = 0; ni < 4; ++ni)
        bn[ni] = Bbuf[cur][((wc * 4 + ni) * 2 + ks) * 64 + lane];
      #pragma unroll
      for (int mi = 0; mi < 4; ++mi)
        #pragma unroll
        for (int ni = 0; ni < 4; ++ni)
          acc[mi][ni] = __builtin_amdgcn_mfma_f32_16x16x32_bf16(
              am[mi], bn[ni], acc[mi][ni], 0, 0, 0);
    }
    __syncthreads();   // next slab landed; all waves done reading cur
  }
  #undef STAGE

  // ---- epilogue: harvest rows (always) and cols (off-diag) ----
  float rSE[4][4], rPOS[4][4];
  float cSE[4] = {0.f, 0.f, 0.f, 0.f};
  float cPOS[4] = {0.f, 0.f, 0.f, 0.f};
  int labn[4][4], labm[4];
  #pragma unroll
  for (int mi = 0; mi < 4; ++mi)
    #pragma unroll
    for (int r = 0; r < 4; ++r) {
      rSE[mi][r] = 0.f; rPOS[mi][r] = 0.f;
      labn[mi][r] = labU[wr * 64 + mi * 16 + lq * 4 + r];
    }
  #pragma unroll
  for (int ni = 0; ni < 4; ++ni) labm[ni] = labV[wc * 64 + ni * 16 + lrow];

  #pragma unroll
  for (int mi = 0; mi < 4; ++mi) {
    const int u_loc = wr * 64 + mi * 16 + lq * 4;
    #pragma unroll
    for (int ni = 0; ni < 4; ++ni) {
      const int v_loc = wc * 64 + ni * 16 + lrow;
      #pragma unroll
      for (int r = 0; r < 4; ++r) {
        const float sim = acc[mi][ni][r] * 10.0f;    // 1/TAU
        const float e = __expf(sim - 10.0f);         // fixed shift (diag max)
        rSE[mi][r] += e;
        const bool match = (labn[mi][r] >= 0) && (labm[ni] == labn[mi][r]);
        const bool self = diag && (u_loc + r == v_loc);
        if (match && !self) rPOS[mi][r] += sim;
        if (!diag) {
          cSE[ni] += e;
          if (match) cPOS[ni] += sim;   // cross-tile: self impossible
        }
      }
    }
  }

  // row reduce across the 16 col-lanes -> lanes lrow==0 hold (mi, lq, r)
  #pragma unroll
  for (int off = 1; off <= 8; off <<= 1)
    #pragma unroll
    for (int mi = 0; mi < 4; ++mi)
      #pragma unroll
      for (int r = 0; r < 4; ++r) {
        rSE[mi][r] += __shfl_xor(rSE[mi][r], off);
        rPOS[mi][r] += __shfl_xor(rPOS[mi][r], off);
      }
  if (lrow == 0) {
    #pragma unroll
    for (int mi = 0; mi < 4; ++mi)
      #pragma unroll
      for (int r = 0; r < 4; ++r) {
        float2 st; st.x = rSE[mi][r]; st.y = rPOS[mi][r];
        rowBuf[wr * 64 + mi * 16 + lq * 4 + r][wc] = st;
      }
  }
  if (!diag) {
    // col reduce across lq groups -> lanes lane<16 hold (ni, lrow)
    #pragma unroll
    for (int off = 16; off <= 32; off <<= 1)
      #pragma unroll
      for (int ni = 0; ni < 4; ++ni) {
        cSE[ni] += __shfl_xor(cSE[ni], off);
        cPOS[ni] += __shfl_xor(cPOS[ni], off);
      }
    if (lane < 16) {
      #pragma unroll
      for (int ni = 0; ni < 4; ++ni) {
        float2 st; st.x = cSE[ni]; st.y = cPOS[ni];
        colBuf[wc * 64 + ni * 16 + lrow][wr] = st;
      }
    }
  }
  __syncthreads();
  if (tid < 128) {
    const float2 ra = rowBuf[tid][0], rb = rowBuf[tid][1];
    float2 st; st.x = ra.x + rb.x; st.y = ra.y + rb.y;
    sp[(size_t)tv * NGID + gbase + tu * 128 + tid] = st;
    if (!diag) {
      const float2 ca = colBuf[tid][0], cb = colBuf[tid][1];
      float2 ct; ct.x = ca.x + cb.x; ct.y = ca.y + cb.y;
      sp[(size_t)tu * NGID + gbase + tv * 128 + tid] = ct;
    }
  }
}

// Sum per-gid partials over slots (5 for scale0, 3 for scale1), apply
// LSE + pos/cnt, reduce. Last block (ticket) folds the final loss scalar.
__global__ __launch_bounds__(256) void loss_reduce(
    const float2* __restrict__ sp, const int* __restrict__ cnt0,
    const int* __restrict__ cnt1, float* __restrict__ acc,
    const int* __restrict__ valid, int* __restrict__ ticket,
    float* __restrict__ lossp) {
  __shared__ float r0[4], r1[4];
  const int t = threadIdx.x;
  float l0 = 0.f, l1 = 0.f;
  for (int g = blockIdx.x * 256 + t; g < NGID; g += 64 * 256) {
    const bool is0 = g < 40960;
    const int n = is0 ? (g % 640) : ((g - 40960) % 384);
    const int nslots = is0 ? 5 : 3;
    float se = 0.f, pos = 0.f;
    for (int s = 0; s < nslots; ++s) {
      const float2 v = sp[(size_t)s * NGID + g];
      se += v.x; pos += v.y;
    }
    const int c = is0 ? cnt0[n] : cnt1[n];
    if (c > 0) {
      const float v = (10.0f + logf(se)) - pos / (float)c;
      if (is0) l0 += v; else l1 += v;
    }
  }
  #pragma unroll
  for (int off = 32; off > 0; off >>= 1) {
    l0 += __shfl_xor(l0, off);
    l1 += __shfl_xor(l1, off);
  }
  if ((t & 63) == 0) { r0[t >> 6] = l0; r1[t >> 6] = l1; }
  __syncthreads();
  if (t == 0) {
    atomicAdd(&acc[0], r0[0] + r0[1] + r0[2] + r0[3]);
    atomicAdd(&acc[1], r1[0] + r1[1] + r1[2] + r1[3]);
    __threadfence();
    const int done = atomicAdd(ticket, 1);
    if (done == 63) {   // last block: fold final loss (atomic reads only)
      const float a0v = atomicAdd(&acc[0], 0.0f);
      const float a1v = atomicAdd(&acc[1], 0.0f);
      float l = 0.f;
      if (valid[0] > 0) l += a0v / (float)(BATCH * valid[0]);
      if (valid[1] > 0) l += a1v / (float)(BATCH * valid[1]);
      lossp[0] = l;
    }
  }
}

extern "C" void kernel_launch(void* const* d_in, const int* in_sizes, int n_in,
                              void* d_out, int out_size, void* d_ws,
                              size_t ws_size, hipStream_t stream) {
  const float* x0 = (const float*)d_in[0];
  const float* x1 = (const float*)d_in[1];
  const float* w0 = (const float*)d_in[2];
  const float* w1 = (const float*)d_in[3];
  const float* ehy0 = (const float*)d_in[4];
  const float* ehy1 = (const float*)d_in[5];
  const float* enod0 = (const float*)d_in[6];
  const float* enod1 = (const float*)d_in[7];

  float* out = (float*)d_out;
  float* adj0 = out;                       // 640*128
  float* adj1 = out + 640 * 128;           // 384*64
  float* lossp = out + 640 * 128 + 384 * 64;

  unsigned short* nhat0 = (unsigned short*)d_ws;
  unsigned short* nhat1 = nhat0 + (size_t)BATCH * 640 * DDIM;
  int* ip = (int*)(nhat1 + (size_t)BATCH * 384 * DDIM);
  int* labels0 = ip;
  int* labels1 = labels0 + 640;
  int* cnt0 = labels1 + 384;
  int* cnt1 = cnt0 + 640;
  int* valid = cnt1 + 384;
  int* ticket = valid + 2;
  float* acc = (float*)(ticket + 1);
  float2* sp = (float2*)((((size_t)(acc + 2)) + 255) & ~(size_t)255);
  // sp: 5 slots x 65536 gids x 8 B = 2.6 MB (ws total ~58 MB)

  prep_kernel<<<1024 + 16384, 256, 0, stream>>>(
      enod0, ehy0, enod1, ehy1, adj0, adj1, labels0, labels1,
      x0, w0, x1, w1, nhat0, nhat1, acc, ticket);
  cnt_kernel<<<2, 256, 0, stream>>>(labels0, cnt0, labels1, cnt1, valid);
  lse_kernel<<<1344, 256, 0, stream>>>(nhat0, labels0, nhat1, labels1, sp);
  loss_reduce<<<64, 256, 0, stream>>>(sp, cnt0, cnt1, acc, valid, ticket,
                                      lossp);
}